// Round 6
// baseline (93.328 us; speedup 1.0000x reference)
//
#include <hip/hip_runtime.h>

// Adaptive avg pool 2D: (16, 768, 64, 48) f32 -> (16, 768, 7, 7) f32.
// 2 planes per wave, barrier-free, non-temporal streaming.
// Lane l owns row l of both planes: 24x global_load_dwordx4 (nt) issue
// back-to-back (24 KB in flight per wave), then per plane: 7 W-window sums in
// registers -> wave-private LDS strip -> wave-local lgkmcnt -> 10-row H-pool
// -> nt store of 49 contiguous floats.

#define H_IN 64
#define W_IN 48
#define HO 7
#define WO 7
#define PLANE (H_IN * W_IN)   // 3072 floats = 12 KB
#define WPB 4                 // waves per block
#define PPW 2                 // planes per wave

typedef float f32x4 __attribute__((ext_vector_type(4)));

__global__ __launch_bounds__(256) void
adaptive_pool_kernel(const float* __restrict__ x, float* __restrict__ out) {
    __shared__ float ts[WPB][H_IN][8];   // wave-private strips, 8 KB

    const int tid  = threadIdx.x;
    const int wid  = tid >> 6;
    const int lane = tid & 63;           // = row index
    const size_t plane0 = (size_t)blockIdx.x * (WPB * PPW) + (size_t)wid * PPW;

    const f32x4* rp0 = reinterpret_cast<const f32x4*>(x + plane0 * PLANE + lane * W_IN);
    const f32x4* rp1 = reinterpret_cast<const f32x4*>(x + (plane0 + 1) * PLANE + lane * W_IN);

    // ---- Issue ALL 24 nt loads up front (24 KB in flight per wave) ----
    f32x4 v0[12], v1[12];
    #pragma unroll
    for (int k = 0; k < 12; ++k) v0[k] = __builtin_nontemporal_load(rp0 + k);
    #pragma unroll
    for (int k = 0; k < 12; ++k) v1[k] = __builtin_nontemporal_load(rp1 + k);

    // W windows (compile-time): [0,7)[6,14)[13,21)[20,28)[27,35)[34,42)[41,48)
    const int WS[WO] = {0, 6, 13, 20, 27, 34, 41};
    const int WE[WO] = {7, 14, 21, 28, 35, 42, 48};

    #pragma unroll
    for (int p = 0; p < PPW; ++p) {
        // Unpack (static indexing -> stays in VGPRs)
        float c[W_IN];
        #pragma unroll
        for (int k = 0; k < 12; ++k) {
            const f32x4 f = p ? v1[k] : v0[k];
            c[4*k+0] = f.x; c[4*k+1] = f.y; c[4*k+2] = f.z; c[4*k+3] = f.w;
        }

        // ---- W-pool: uniform, divergence-free ----
        float w[WO];
        #pragma unroll
        for (int o = 0; o < WO; ++o) {
            float s = 0.0f;
            #pragma unroll
            for (int j = WS[o]; j < WE[o]; ++j) s += c[j];
            w[o] = s * (1.0f / (float)(WE[o] - WS[o]));
        }

        // ---- Strip to wave-private LDS ----
        *reinterpret_cast<f32x4*>(&ts[wid][lane][0]) = (f32x4){w[0], w[1], w[2], w[3]};
        ts[wid][lane][4] = w[4];
        ts[wid][lane][5] = w[5];
        ts[wid][lane][6] = w[6];

        asm volatile("s_waitcnt lgkmcnt(0)" ::: "memory");
        __builtin_amdgcn_wave_barrier();

        // ---- H-pool: 49 outputs, window always 10 rows ----
        if (lane < HO * WO) {
            const int oh = lane / WO;
            const int ow = lane % WO;
            const int hs = (oh * H_IN) / HO;   // 0,9,18,27,36,45,54
            float s = 0.0f;
            #pragma unroll
            for (int h = 0; h < 10; ++h) s += ts[wid][hs + h][ow];
            __builtin_nontemporal_store(s * 0.1f, out + (plane0 + p) * (HO * WO) + lane);
        }

        // Keep this plane's LDS reads ordered before next plane's strip writes
        // (cross-lane WAR not visible to the compiler; DS ops are in-order per
        // wave at HW level, wave_barrier pins the compiler's schedule).
        __builtin_amdgcn_wave_barrier();
    }
}

extern "C" void kernel_launch(void* const* d_in, const int* in_sizes, int n_in,
                              void* d_out, int out_size, void* d_ws, size_t ws_size,
                              hipStream_t stream) {
    const float* x = (const float*)d_in[0];
    float* out = (float*)d_out;
    const int nplanes = in_sizes[0] / PLANE;         // 12288
    const int nblocks = nplanes / (WPB * PPW);       // 1536
    adaptive_pool_kernel<<<nblocks, 256, 0, stream>>>(x, out);
}

// Round 7
// 30.918 us; speedup vs baseline: 3.0185x; 3.0185x over previous
//
#include <hip/hip_runtime.h>

// Adaptive avg pool 2D: (16, 768, 64, 48) f32 -> (16, 768, 7, 7) f32.
// 2 planes per wave, barrier-free. Lane l owns row l of both planes:
// 24x global_load_dwordx4 issue back-to-back (24 KB in flight per wave), then
// per plane: 7 W-window sums in registers -> wave-private LDS strip ->
// wave-local lgkmcnt -> 10-row H-pool -> store 49 contiguous floats.

#define H_IN 64
#define W_IN 48
#define HO 7
#define WO 7
#define PLANE (H_IN * W_IN)   // 3072 floats = 12 KB
#define WPB 4                 // waves per block
#define PPW 2                 // planes per wave

typedef float f32x4 __attribute__((ext_vector_type(4)));

__global__ __launch_bounds__(256) void
adaptive_pool_kernel(const float* __restrict__ x, float* __restrict__ out) {
    __shared__ float ts[WPB][H_IN][8];   // wave-private strips, 8 KB

    const int tid  = threadIdx.x;
    const int wid  = tid >> 6;
    const int lane = tid & 63;           // = row index
    const size_t plane0 = (size_t)blockIdx.x * (WPB * PPW) + (size_t)wid * PPW;

    const f32x4* rp0 = reinterpret_cast<const f32x4*>(x + plane0 * PLANE + lane * W_IN);
    const f32x4* rp1 = reinterpret_cast<const f32x4*>(x + (plane0 + 1) * PLANE + lane * W_IN);

    // ---- Issue ALL 24 loads up front (24 KB in flight per wave) ----
    f32x4 v0[12], v1[12];
    #pragma unroll
    for (int k = 0; k < 12; ++k) v0[k] = rp0[k];
    #pragma unroll
    for (int k = 0; k < 12; ++k) v1[k] = rp1[k];

    // W windows (compile-time): [0,7)[6,14)[13,21)[20,28)[27,35)[34,42)[41,48)
    const int WS[WO] = {0, 6, 13, 20, 27, 34, 41};
    const int WE[WO] = {7, 14, 21, 28, 35, 42, 48};

    #pragma unroll
    for (int p = 0; p < PPW; ++p) {
        // Unpack (static indexing -> stays in VGPRs)
        float c[W_IN];
        #pragma unroll
        for (int k = 0; k < 12; ++k) {
            const f32x4 f = p ? v1[k] : v0[k];
            c[4*k+0] = f.x; c[4*k+1] = f.y; c[4*k+2] = f.z; c[4*k+3] = f.w;
        }

        // ---- W-pool: uniform, divergence-free ----
        float w[WO];
        #pragma unroll
        for (int o = 0; o < WO; ++o) {
            float s = 0.0f;
            #pragma unroll
            for (int j = WS[o]; j < WE[o]; ++j) s += c[j];
            w[o] = s * (1.0f / (float)(WE[o] - WS[o]));
        }

        // ---- Strip to wave-private LDS ----
        *reinterpret_cast<f32x4*>(&ts[wid][lane][0]) = (f32x4){w[0], w[1], w[2], w[3]};
        ts[wid][lane][4] = w[4];
        ts[wid][lane][5] = w[5];
        ts[wid][lane][6] = w[6];

        asm volatile("s_waitcnt lgkmcnt(0)" ::: "memory");
        __builtin_amdgcn_wave_barrier();

        // ---- H-pool: 49 outputs, window always 10 rows ----
        if (lane < HO * WO) {
            const int oh = lane / WO;
            const int ow = lane % WO;
            const int hs = (oh * H_IN) / HO;   // 0,9,18,27,36,45,54
            float s = 0.0f;
            #pragma unroll
            for (int h = 0; h < 10; ++h) s += ts[wid][hs + h][ow];
            out[(plane0 + p) * (HO * WO) + lane] = s * 0.1f;
        }

        // Keep this plane's LDS reads ordered before next plane's strip writes.
        __builtin_amdgcn_wave_barrier();
    }
}

extern "C" void kernel_launch(void* const* d_in, const int* in_sizes, int n_in,
                              void* d_out, int out_size, void* d_ws, size_t ws_size,
                              hipStream_t stream) {
    const float* x = (const float*)d_in[0];
    float* out = (float*)d_out;
    const int nplanes = in_sizes[0] / PLANE;         // 12288
    const int nblocks = nplanes / (WPB * PPW);       // 1536
    adaptive_pool_kernel<<<nblocks, 256, 0, stream>>>(x, out);
}

// Round 8
// 29.220 us; speedup vs baseline: 3.1940x; 1.0581x over previous
//
#include <hip/hip_runtime.h>

// Adaptive avg pool 2D: (16, 768, 64, 48) f32 -> (16, 768, 7, 7) f32.
// Persistent wave-per-row, register ping-pong pipeline, NPL=3 planes/wave.
// Lane l owns row l. Buffers X,Y (12 x f32x4 each): load X(p0), load Y(p1),
// compute X (reload X <- p2 issues right after X is consumed, flying under
// the rest of p0's compute and all of p1's), compute Y, compute X.
// Waves keep ~12 loads outstanding nearly continuously. No block barriers.

#define H_IN 64
#define W_IN 48
#define HO 7
#define WO 7
#define PLANE (H_IN * W_IN)   // 3072 floats = 12 KB
#define WPB 4                 // waves per block
#define NPL 3                 // planes per wave

typedef float f32x4 __attribute__((ext_vector_type(4)));

__global__ __launch_bounds__(256) void
adaptive_pool_kernel(const float* __restrict__ x, float* __restrict__ out) {
    __shared__ float ts[WPB][H_IN][8];   // wave-private strips, 8 KB

    const int tid  = threadIdx.x;
    const int wid  = tid >> 6;
    const int lane = tid & 63;           // = row index
    const size_t plane0 = ((size_t)blockIdx.x * WPB + wid) * NPL;
    const float* rowbase = x + plane0 * PLANE + (size_t)lane * W_IN;

    f32x4 X[12], Y[12];

    // ---- Prologue: fill both buffers (24 loads in flight) ----
    #pragma unroll
    for (int k = 0; k < 12; ++k) X[k] = reinterpret_cast<const f32x4*>(rowbase)[k];
    #pragma unroll
    for (int k = 0; k < 12; ++k) Y[k] = reinterpret_cast<const f32x4*>(rowbase + PLANE)[k];

    // W windows (compile-time): [0,7)[6,14)[13,21)[20,28)[27,35)[34,42)[41,48)
    const int WS[WO] = {0, 6, 13, 20, 27, 34, 41};
    const int WE[WO] = {7, 14, 21, 28, 35, 42, 48};

    auto compute = [&](const f32x4 (&v)[12], int p) {
        // Unpack (SSA values, stays in VGPRs). After this, the buffer regs are
        // dead -> the next load into them can issue (WAR) and fly under the
        // rest of this plane's work.
        float c[W_IN];
        #pragma unroll
        for (int k = 0; k < 12; ++k) {
            c[4*k+0] = v[k].x; c[4*k+1] = v[k].y; c[4*k+2] = v[k].z; c[4*k+3] = v[k].w;
        }
        // W-pool: uniform, divergence-free
        float w[WO];
        #pragma unroll
        for (int o = 0; o < WO; ++o) {
            float s = 0.0f;
            #pragma unroll
            for (int j = WS[o]; j < WE[o]; ++j) s += c[j];
            w[o] = s * (1.0f / (float)(WE[o] - WS[o]));
        }
        // Strip to wave-private LDS
        *reinterpret_cast<f32x4*>(&ts[wid][lane][0]) = (f32x4){w[0], w[1], w[2], w[3]};
        ts[wid][lane][4] = w[4];
        ts[wid][lane][5] = w[5];
        ts[wid][lane][6] = w[6];

        asm volatile("s_waitcnt lgkmcnt(0)" ::: "memory");
        __builtin_amdgcn_wave_barrier();

        // H-pool: 49 outputs, window always 10 rows
        if (lane < HO * WO) {
            const int oh = lane / WO;
            const int ow = lane % WO;
            const int hs = (oh * H_IN) / HO;   // 0,9,18,27,36,45,54
            float s = 0.0f;
            #pragma unroll
            for (int h = 0; h < 10; ++h) s += ts[wid][hs + h][ow];
            out[(plane0 + p) * (HO * WO) + lane] = s * 0.1f;
        }
        // Order this plane's LDS reads before the next plane's strip writes.
        __builtin_amdgcn_wave_barrier();
    };

    // ---- Pipelined steady state ----
    compute(X, 0);
    #pragma unroll
    for (int k = 0; k < 12; ++k) X[k] = reinterpret_cast<const f32x4*>(rowbase + 2 * PLANE)[k];
    compute(Y, 1);
    compute(X, 2);
}

extern "C" void kernel_launch(void* const* d_in, const int* in_sizes, int n_in,
                              void* d_out, int out_size, void* d_ws, size_t ws_size,
                              hipStream_t stream) {
    const float* x = (const float*)d_in[0];
    float* out = (float*)d_out;
    const int nplanes = in_sizes[0] / PLANE;         // 12288
    const int nblocks = nplanes / (WPB * NPL);       // 1024
    adaptive_pool_kernel<<<nblocks, 256, 0, stream>>>(x, out);
}